// Round 9
// baseline (359.851 us; speedup 1.0000x reference)
//
#include <hip/hip_runtime.h>
#include <hip/hip_fp8.h>

typedef _Float16 h16;
typedef _Float16 h16x8 __attribute__((ext_vector_type(8)));
typedef _Float16 h16x4 __attribute__((ext_vector_type(4)));
typedef float f32x4 __attribute__((ext_vector_type(4)));
typedef float f32x2 __attribute__((ext_vector_type(2)));

#define DEV static __device__ __forceinline__

// ---- workspace layout (h16 element offsets) ----
// Weight slabs: per-op, per-64-col n-stripe contiguous [nl][K] with the k-chunk
// XOR swizzle (chunk p = c ^ (nl&7)) baked in so a LINEAR global->LDS DMA
// reproduces the bank-spread LDS image.
static constexpr size_t OFF_DATA  = 0;          // 16384*256  data (f16)
static constexpr size_t SLAB_W0   = 4194304;    // 512*256
static constexpr size_t SLAB_W1   = 4325376;    // 512*512
static constexpr size_t SLAB_W2   = 4587520;    // 512*512
static constexpr size_t SLAB_PD   = 4849664;    // 512*256 (x2 baked)
static constexpr size_t SLAB_QKV  = 4980736;    // 1536*512
static constexpr size_t SLAB_OW   = 5767168;    // 512*512
static constexpr size_t SLAB_PI   = 6029312;    // 512*256
static constexpr size_t OFF_X1    = 6160384;    // 16384*512  X1 / kv8(bytes)
static constexpr size_t OFF_X2    = 14548992;   // 16384*512  X2 / PRE2
static constexpr size_t OFF_P     = 22937600;   // 16384*512  P / LOCAL / ATTN
// total: 31,326,208 elems = ~60 MB

DEV void gload16(const void* g, void* l)
{
    __builtin_amdgcn_global_load_lds(
        (__attribute__((address_space(1))) void*)(void*)g,
        (__attribute__((address_space(3))) void*)l, 16, 0, 0);
}

DEV float eluf(float x) { return x > 0.f ? x : __expf(x) - 1.f; }

// ---- data fp32 -> f16 ----
__global__ __launch_bounds__(256)
void k_cvt_data(const float* __restrict__ src, h16* __restrict__ dst)
{
    size_t i = ((size_t)blockIdx.x * 256 + threadIdx.x) * 4;
    float4 v = *(const float4*)(src + i);
    h16x4 o;
    o[0] = (h16)v.x; o[1] = (h16)v.y; o[2] = (h16)v.z; o[3] = (h16)v.w;
    *(h16x4*)(dst + i) = o;
}

// ---- weight prep: W[K][512] fp32 -> swizzled f16 slabs ----
// Slab layout: stripe ns (64 cols) base = ns*64*K; row nl (col within stripe)
// base = nl*K; 8-elem chunk c (k = c*8+e) stored at position p = c ^ (nl&7).
__global__ void k_prep_w(const float* __restrict__ w0, const float* __restrict__ w1,
                         const float* __restrict__ w2, const float* __restrict__ pdw,
                         const float* __restrict__ qw, const float* __restrict__ kw,
                         const float* __restrict__ vw, const float* __restrict__ ow,
                         const float* __restrict__ piw, h16* __restrict__ ws)
{
    const int b = blockIdx.x;
    const float* src; size_t dstBase; int K, tb; float scale = 1.f;
    if (b < 32)       { src = w0;  dstBase = SLAB_W0;           K = 256; tb = 0; }
    else if (b < 96)  { src = w1;  dstBase = SLAB_W1;           K = 512; tb = 32; }
    else if (b < 160) { src = w2;  dstBase = SLAB_W2;           K = 512; tb = 96; }
    else if (b < 192) { src = pdw; dstBase = SLAB_PD;           K = 256; scale = 2.f; tb = 160; }
    else if (b < 256) { src = qw;  dstBase = SLAB_QKV;          K = 512; tb = 192; }
    else if (b < 320) { src = kw;  dstBase = SLAB_QKV + 262144; K = 512; tb = 256; }
    else if (b < 384) { src = vw;  dstBase = SLAB_QKV + 524288; K = 512; tb = 320; }
    else if (b < 448) { src = ow;  dstBase = SLAB_OW;           K = 512; tb = 384; }
    else              { src = piw; dstBase = SLAB_PI;           K = 256; tb = 448; }
    const int t = b - tb;
    const int ktiles = K >> 6;
    const int kt = t % ktiles, nt = t / ktiles;
    __shared__ float tile[64][65];
    const int tid = threadIdx.x;
    #pragma unroll
    for (int r = 0; r < 16; ++r) {
        const int idx = r * 256 + tid;
        const int kk = idx >> 6, nn = idx & 63;
        tile[kk][nn] = src[(size_t)(kt * 64 + kk) * 512 + nt * 64 + nn] * scale;
    }
    __syncthreads();
    #pragma unroll
    for (int r = 0; r < 2; ++r) {
        const int ch = r * 256 + tid;
        const int nl = ch >> 3, cl = ch & 7;
        const int c  = kt * 8 + cl;
        const int p  = c ^ (nl & 7);
        h16x8 o;
        #pragma unroll
        for (int e = 0; e < 8; ++e) o[e] = (h16)tile[cl * 8 + e][nl];
        *(h16x8*)&ws[dstBase + (size_t)nt * 64 * K + (size_t)nl * K + p * 8] = o;
    }
}

// ---- weights-resident GEMM with 2-deep A prefetch ----
// Block = 64-col n-stripe x 256 rows; 4 waves, each 64m x 64n (4x4 16x16x32
// frags, 16 MFMA/k-step). Whole 64xK weight slab DMA'd to LDS once, ONE
// barrier, then a barrier-free K loop: A frags global->VGPR with an explicit
// 2-iteration software pipeline (loads for ks+2 issued before MFMAs of ks,
// ~2x16 MFMA of latency cover), B frags from the XOR-swizzled LDS slab.
// Same-mg blocks are XCD-colocated (idx%8) so A stays L2-resident.
// BIASMODE: 0 = bias1[col]; 1 = bias1 + s*bias2; 2 = qkv split (ns<8 -> Q h16,
//           else fp8 K|V into out2[row*1024 + col-512]); 3 = none.
// ACC: out += (two-pass concat-K replacement).
template<int K, int BIASMODE, bool DOELU, bool ACC>
__global__ __launch_bounds__(256, 2)
void k_gemm(const h16* __restrict__ A, const h16* __restrict__ slab,
            const float* __restrict__ bias1, const float* __restrict__ bias2,
            const float* __restrict__ bias3, const float s,
            h16* __restrict__ out, unsigned char* __restrict__ out2, const int NT)
{
    constexpr int NK = K / 32;
    __shared__ __align__(16) h16 sB[64 * K];
    const int tid = threadIdx.x, lane = tid & 63, w = tid >> 6;
    const int slot = blockIdx.x & 7, gg = blockIdx.x >> 3;
    const int mg = (gg / NT) * 8 + slot;     // 0..63 ; same-mg -> same XCD
    const int ns = gg % NT;

    const char* g = (const char*)(slab + (size_t)ns * 64 * K);
    #pragma unroll
    for (int r = 0; r < K / 32; ++r)
        gload16(g + r * 4096 + tid * 16, (char*)sB + r * 4096 + tid * 16);
    __syncthreads();   // drains the slab DMA

    const int lm = lane & 15, lq = lane >> 4;
    const int mBase = mg * 256 + w * 64;
    const f32x4 zero = {0.f, 0.f, 0.f, 0.f};
    f32x4 acc[4][4];
    #pragma unroll
    for (int i = 0; i < 4; ++i) {
        #pragma unroll
        for (int j = 0; j < 4; ++j) acc[i][j] = zero;
    }

    const h16* Ar[4];
    #pragma unroll
    for (int i = 0; i < 4; ++i)
        Ar[i] = A + (size_t)(mBase + i * 16 + lm) * K + lq * 8;

    h16x8 aP[4], aQ[4];
    #pragma unroll
    for (int i = 0; i < 4; ++i) aP[i] = *(const h16x8*)(Ar[i]);
    #pragma unroll
    for (int i = 0; i < 4; ++i) aQ[i] = *(const h16x8*)(Ar[i] + 32);

    for (int ks = 0; ks < NK; ++ks) {
        h16x8 aC[4];
        #pragma unroll
        for (int i = 0; i < 4; ++i) aC[i] = aP[i];
        #pragma unroll
        for (int i = 0; i < 4; ++i) aP[i] = aQ[i];
        if (ks + 2 < NK) {
            #pragma unroll
            for (int i = 0; i < 4; ++i) aQ[i] = *(const h16x8*)(Ar[i] + (ks + 2) * 32);
        }
        h16x8 bf[4];
        #pragma unroll
        for (int j = 0; j < 4; ++j) {
            const int nl = j * 16 + lm;
            bf[j] = *(const h16x8*)&sB[nl * K + (((ks * 4 + lq) ^ (lm & 7)) << 3)];
        }
        #pragma unroll
        for (int i = 0; i < 4; ++i) {
            #pragma unroll
            for (int j = 0; j < 4; ++j)
                acc[i][j] = __builtin_amdgcn_mfma_f32_16x16x32_f16(aC[i], bf[j], acc[i][j], 0, 0, 0);
        }
    }

    const int lr4 = lq * 4;
    #pragma unroll
    for (int j = 0; j < 4; ++j) {
        const int col = ns * 64 + j * 16 + lm;
        float bv = 0.f;
        if (BIASMODE == 0) bv = bias1[col];
        else if (BIASMODE == 1) bv = bias1[col] + s * bias2[col];
        else if (BIASMODE == 2) {
            const float* bp = ns < 8 ? bias1 : (ns < 16 ? bias2 : bias3);
            bv = bp[col & 511];
        }
        #pragma unroll
        for (int i = 0; i < 4; ++i) {
            const int row0 = mBase + i * 16 + lr4;
            #pragma unroll
            for (int r = 0; r < 4; ++r) {
                float v = acc[i][j][r] + bv;
                if (DOELU) v = eluf(v);
                if (BIASMODE == 2) {
                    if (ns < 8) {
                        out[(size_t)(row0 + r) * 512 + col] = (h16)v;
                    } else {
                        __hip_fp8_e4m3 f8(v);
                        out2[(size_t)(row0 + r) * 1024 + (col - 512)] = (unsigned char)f8.__x;
                    }
                } else {
                    const size_t o = (size_t)(row0 + r) * 512 + col;
                    if (ACC) v += (float)out[o];
                    out[o] = (h16)v;
                }
            }
        }
    }
}

// ---- layernorm (one wave per 512-row), optional ELU, optional fp32 out ----
template<bool DOELU, bool OUTF32>
__global__ __launch_bounds__(256)
void k_ln(const h16* __restrict__ X, const float* __restrict__ g, const float* __restrict__ b,
          h16* __restrict__ outH, float* __restrict__ outF)
{
    const int row  = blockIdx.x * 4 + (threadIdx.x >> 6);
    const int lane = threadIdx.x & 63;
    const h16x8 xv = *(const h16x8*)(X + (size_t)row * 512 + lane * 8);
    float v[8], s = 0.f, ss = 0.f;
    #pragma unroll
    for (int k = 0; k < 8; ++k) { v[k] = (float)xv[k]; s += v[k]; ss += v[k] * v[k]; }
    #pragma unroll
    for (int m = 1; m < 64; m <<= 1) { s += __shfl_xor(s, m, 64); ss += __shfl_xor(ss, m, 64); }
    const float mean = s * (1.f / 512.f);
    const float var  = ss * (1.f / 512.f) - mean * mean;
    const float rstd = rsqrtf(var + 1e-5f);
    #pragma unroll
    for (int k = 0; k < 8; ++k) {
        const int c = lane * 8 + k;
        float y = (v[k] - mean) * rstd * g[c] + b[c];
        if (DOELU) y = eluf(y);
        if (OUTF32) outF[(size_t)row * 512 + c] = y;
        else        outH[(size_t)row * 512 + c] = (h16)y;
    }
}

// ---- neighbor multi-head attention: ONE WAVE PER NODE, fp8 KV, async LDS gather ----
// fp8 decode via v_cvt_pk_f32_fp8 (4 insts / 8 elems) to cut VALU pressure.
__global__ __launch_bounds__(64)
void k_attn(const h16* __restrict__ Q, const unsigned char* __restrict__ KV,
            const int* __restrict__ nbr, h16* __restrict__ outA)
{
    __shared__ __align__(16) unsigned char sKV[16 * 1024];
    const int n = blockIdx.x;
    const int lane = threadIdx.x;

    #pragma unroll
    for (int j = 0; j < 16; ++j) {
        const int idx = nbr[n * 16 + j];              // wave-uniform -> s_load
        gload16(KV + (size_t)idx * 1024 + lane * 16, &sKV[j * 1024 + lane * 16]);
    }
    const h16x8 qv = *(const h16x8*)&Q[(size_t)n * 512 + lane * 8];

    asm volatile("s_waitcnt vmcnt(0)" ::: "memory");

    float qf[8];
    #pragma unroll
    for (int e = 0; e < 8; ++e) qf[e] = (float)qv[e];

    float s[16];
    #pragma unroll
    for (int j = 0; j < 16; ++j) {
        const uint2 U = *(const uint2*)&sKV[j * 1024 + lane * 8];
        const f32x2 k0 = __builtin_amdgcn_cvt_pk_f32_fp8(U.x, false);
        const f32x2 k1 = __builtin_amdgcn_cvt_pk_f32_fp8(U.x, true);
        const f32x2 k2 = __builtin_amdgcn_cvt_pk_f32_fp8(U.y, false);
        const f32x2 k3 = __builtin_amdgcn_cvt_pk_f32_fp8(U.y, true);
        s[j] = qf[0] * k0.x + qf[1] * k0.y + qf[2] * k1.x + qf[3] * k1.y
             + qf[4] * k2.x + qf[5] * k2.y + qf[6] * k3.x + qf[7] * k3.y;
    }
    #pragma unroll
    for (int m = 1; m < 8; m <<= 1) {
        #pragma unroll
        for (int j = 0; j < 16; ++j) s[j] += __shfl_xor(s[j], m, 64);
    }
    float mx = -1e30f;
    #pragma unroll
    for (int j = 0; j < 16; ++j) { s[j] *= 0.125f; mx = fmaxf(mx, s[j]); }
    float sum = 0.f;
    #pragma unroll
    for (int j = 0; j < 16; ++j) { s[j] = __expf(s[j] - mx); sum += s[j]; }
    const float rinv = 1.f / sum;

    float acc[8];
    #pragma unroll
    for (int e = 0; e < 8; ++e) acc[e] = 0.f;
    #pragma unroll
    for (int j = 0; j < 16; ++j) {
        const float w = s[j] * rinv;
        const uint2 U = *(const uint2*)&sKV[j * 1024 + 512 + lane * 8];
        const f32x2 v0 = __builtin_amdgcn_cvt_pk_f32_fp8(U.x, false);
        const f32x2 v1 = __builtin_amdgcn_cvt_pk_f32_fp8(U.x, true);
        const f32x2 v2 = __builtin_amdgcn_cvt_pk_f32_fp8(U.y, false);
        const f32x2 v3 = __builtin_amdgcn_cvt_pk_f32_fp8(U.y, true);
        acc[0] += w * v0.x; acc[1] += w * v0.y; acc[2] += w * v1.x; acc[3] += w * v1.y;
        acc[4] += w * v2.x; acc[5] += w * v2.y; acc[6] += w * v3.x; acc[7] += w * v3.y;
    }
    h16x8 o;
    #pragma unroll
    for (int e = 0; e < 8; ++e) o[e] = (h16)acc[e];
    *(h16x8*)&outA[(size_t)n * 512 + lane * 8] = o;
}

extern "C" void kernel_launch(void* const* d_in, const int* in_sizes, int n_in,
                              void* d_out, int out_size, void* d_ws, size_t ws_size,
                              hipStream_t stream)
{
    const float* data = (const float*)d_in[0];
    const int*   nbr  = (const int*)d_in[1];
    const float* w0   = (const float*)d_in[2];
    const float* b0   = (const float*)d_in[3];
    const float* w1   = (const float*)d_in[4];
    const float* b1   = (const float*)d_in[5];
    const float* w2   = (const float*)d_in[6];
    const float* b2   = (const float*)d_in[7];
    const float* pdw  = (const float*)d_in[8];
    const float* pdb  = (const float*)d_in[9];
    const float* piw  = (const float*)d_in[10];
    const float* pib  = (const float*)d_in[11];
    const float* qw   = (const float*)d_in[12];
    const float* qb   = (const float*)d_in[13];
    const float* kw   = (const float*)d_in[14];
    const float* kb   = (const float*)d_in[15];
    const float* vw   = (const float*)d_in[16];
    const float* vb   = (const float*)d_in[17];
    const float* ow   = (const float*)d_in[18];
    const float* ob   = (const float*)d_in[19];
    const float* ln1g = (const float*)d_in[20];
    const float* ln1b = (const float*)d_in[21];
    const float* ln2g = (const float*)d_in[22];
    const float* ln2b = (const float*)d_in[23];
    h16*   ws  = (h16*)d_ws;
    float* out = (float*)d_out;
    h16*   qbuf = (h16*)d_out;                          // Q parks in d_out until attn
    unsigned char* kv8 = (unsigned char*)(ws + OFF_X1); // fp8 K|V (X1 dead by then)

    k_cvt_data<<<4096, 256, 0, stream>>>(data, ws + OFF_DATA);
    k_prep_w<<<480, 256, 0, stream>>>(w0, w1, w2, pdw, qw, kw, vw, ow, piw, ws);

    // X1 = elu(data @ W0 + b0)
    k_gemm<256, 0, true , false><<<512, 256, 0, stream>>>(ws + OFF_DATA, ws + SLAB_W0,
                                                          b0, nullptr, nullptr, 0.f,
                                                          ws + OFF_X1, nullptr, 8);
    // X2 = elu(X1 @ W1 + b1)
    k_gemm<512, 0, true , false><<<512, 256, 0, stream>>>(ws + OFF_X1, ws + SLAB_W1,
                                                          b1, nullptr, nullptr, 0.f,
                                                          ws + OFF_X2, nullptr, 8);
    // P = 2*(data @ pd_w) + (b2 + 2*pd_b)        (pass 1; x2 baked into slab)
    k_gemm<256, 1, false, false><<<512, 256, 0, stream>>>(ws + OFF_DATA, ws + SLAB_PD,
                                                          b2, pdb, nullptr, 2.f,
                                                          ws + OFF_P, nullptr, 8);
    // P += X2 @ W2                                (pass 2, accumulate)
    k_gemm<512, 3, false, true ><<<512, 256, 0, stream>>>(ws + OFF_X2, ws + SLAB_W2,
                                                          nullptr, nullptr, nullptr, 0.f,
                                                          ws + OFF_P, nullptr, 8);
    // LOCAL = elu(LN(P))  (in-place)
    k_ln<true, false><<<4096, 256, 0, stream>>>(ws + OFF_P, ln1g, ln1b, ws + OFF_P, nullptr);
    // Q(d_out, f16) | KV8(fp8) = LOCAL @ [q|k|v] + bias
    k_gemm<512, 2, false, false><<<1536, 256, 0, stream>>>(ws + OFF_P, ws + SLAB_QKV,
                                                           qb, kb, vb, 0.f,
                                                           qbuf, kv8, 24);
    // ATTN (-> P region, LOCAL dead)
    k_attn<<<16384, 64, 0, stream>>>(qbuf, kv8, nbr, ws + OFF_P);
    // PRE2 = data @ pi_w + (o_b + pi_b)           (pass 1 -> X2, X2 dead)
    k_gemm<256, 1, false, false><<<512, 256, 0, stream>>>(ws + OFF_DATA, ws + SLAB_PI,
                                                          ob, pib, nullptr, 1.f,
                                                          ws + OFF_X2, nullptr, 8);
    // PRE2 += ATTN @ o_w                          (pass 2, accumulate)
    k_gemm<512, 3, false, true ><<<512, 256, 0, stream>>>(ws + OFF_P, ws + SLAB_OW,
                                                          nullptr, nullptr, nullptr, 0.f,
                                                          ws + OFF_X2, nullptr, 8);
    // out = LN(PRE2)  fp32
    k_ln<false, true><<<4096, 256, 0, stream>>>(ws + OFF_X2, ln2g, ln2b, nullptr, out);
}

// Round 10
// 277.958 us; speedup vs baseline: 1.2946x; 1.2946x over previous
//
#include <hip/hip_runtime.h>
#include <hip/hip_fp8.h>

typedef _Float16 h16;
typedef _Float16 h16x8 __attribute__((ext_vector_type(8)));
typedef _Float16 h16x4 __attribute__((ext_vector_type(4)));
typedef float f32x4 __attribute__((ext_vector_type(4)));
typedef float f32x2 __attribute__((ext_vector_type(2)));

#define DEV static __device__ __forceinline__

// ---- workspace layout (h16 element offsets) ----
static constexpr size_t OFF_DATA = 0;          // 16384*256        data (f16)
static constexpr size_t OFF_W0T  = 4194304;    // 512*256          mlp_w0^T
static constexpr size_t OFF_W1T  = 4325376;    // 512*512          mlp_w1^T
static constexpr size_t OFF_W2PD = 4587520;    // 512*768          [mlp_w2 ; 2*pd_w]^T
static constexpr size_t OFF_QKVT = 4980736;    // 1536*512         [q|k|v]^T
static constexpr size_t OFF_OPIT = 5767168;    // 512*768          [o_w ; pi_w]^T
static constexpr size_t OFF_X1   = 6160384;    // 16384*512  X1 / kv8(bytes) / PRE2
static constexpr size_t OFF_X2   = 14548992;   // 16384*512  X2
static constexpr size_t OFF_P    = 22937600;   // 16384*512  P / LOCAL(in-place) / ATTN
// total: 31,326,208 elems = ~60 MB

DEV void gload16(const void* g, void* l)
{
    __builtin_amdgcn_global_load_lds(
        (__attribute__((address_space(1))) void*)(void*)g,
        (__attribute__((address_space(3))) void*)l, 16, 0, 0);
}

DEV float eluf(float x) { return x > 0.f ? x : __expf(x) - 1.f; }

// ---- data fp32 -> f16 ----
__global__ __launch_bounds__(256)
void k_cvt_data(const float* __restrict__ src, h16* __restrict__ dst)
{
    size_t i = ((size_t)blockIdx.x * 256 + threadIdx.x) * 4;
    float4 v = *(const float4*)(src + i);
    h16x4 o;
    o[0] = (h16)v.x; o[1] = (h16)v.y; o[2] = (h16)v.z; o[3] = (h16)v.w;
    *(h16x4*)(dst + i) = o;
}

// ---- all weight transposes (src [K][512] fp32 -> dst [n][k] f16, optional scale) ----
__global__ void k_prep_w(const float* __restrict__ w0, const float* __restrict__ w1,
                         const float* __restrict__ w2, const float* __restrict__ pdw,
                         const float* __restrict__ qw, const float* __restrict__ kw,
                         const float* __restrict__ vw, const float* __restrict__ ow,
                         const float* __restrict__ piw, h16* __restrict__ ws)
{
    int b = blockIdx.x;
    const float* src; h16* dst; int K, dstStride, dstKOff = 0, tb; float scale = 1.f;
    const int N = 512;
    if (b < 128)       { src = w0;  dst = ws + OFF_W0T;           K = 256; dstStride = 256; tb = 0; }
    else if (b < 384)  { src = w1;  dst = ws + OFF_W1T;           K = 512; dstStride = 512; tb = 128; }
    else if (b < 640)  { src = w2;  dst = ws + OFF_W2PD;          K = 512; dstStride = 768; tb = 384; }
    else if (b < 768)  { src = pdw; dst = ws + OFF_W2PD;          K = 256; dstStride = 768; dstKOff = 512; scale = 2.f; tb = 640; }
    else if (b < 1024) { src = qw;  dst = ws + OFF_QKVT;          K = 512; dstStride = 512; tb = 768; }
    else if (b < 1280) { src = kw;  dst = ws + OFF_QKVT + 262144; K = 512; dstStride = 512; tb = 1024; }
    else if (b < 1536) { src = vw;  dst = ws + OFF_QKVT + 524288; K = 512; dstStride = 512; tb = 1280; }
    else if (b < 1792) { src = ow;  dst = ws + OFF_OPIT;          K = 512; dstStride = 768; tb = 1536; }
    else               { src = piw; dst = ws + OFF_OPIT;          K = 256; dstStride = 768; dstKOff = 512; tb = 1792; }
    int t = b - tb;
    int tilesK = K >> 5;
    int tk = t % tilesK, tn = t / tilesK;
    __shared__ float tile[32][33];
    int tx = threadIdx.x, ty = threadIdx.y;
    #pragma unroll
    for (int r = 0; r < 32; r += 8)
        tile[ty + r][tx] = src[(size_t)(tk * 32 + ty + r) * N + tn * 32 + tx] * scale;
    __syncthreads();
    #pragma unroll
    for (int r = 0; r < 32; r += 8) {
        int n = tn * 32 + ty + r, k = tk * 32 + tx;
        dst[(size_t)n * dstStride + dstKOff + k] = (h16)tile[tx][ty + r];
    }
}

// ---- GEMM: C[M,N] = concat(A1[K1],A2[K2]) @ BT^T + bias (r7 structure) ----
// Tile 64(m) x 128(n), 256 threads = 4 waves (2m x 2n), wave = 32x64 via
// 2x4 MFMA 16x16x32 subtiles. BK=64 as two stride-32 slabs (global_load_lds
// lane*16 contiguity preserved). 16 MFMA per barrier-pair per wave; 1024
// blocks (N=512) -> 4 blocks/CU of overlapping barrier groups.
// 1D grid; swizzle keeps the NT n-blocks of one m-stripe on one XCD.
// BIASMODE: 0 = bias1[col]; 1 = bias1[col] + b2scale*bias2[col];
//           2 = segmented qkv bias + split output: cols 0..511 -> out (h16 Q),
//               cols 512..1535 -> out2 (fp8 e4m3 K|V, row*1024 + col-512)
template<int BIASMODE, bool DOELU, int NT>
__global__ __launch_bounds__(256, 4)
void k_gemm(const h16* __restrict__ A1, const h16* __restrict__ A2,
            const int K1, const int K2,
            const h16* __restrict__ BT,
            const float* __restrict__ bias1, const float* __restrict__ bias2,
            const float* __restrict__ bias3, const float b2scale,
            h16* __restrict__ out, unsigned char* __restrict__ out2, const int N)
{
    const int Kt = K1 + K2;
    __shared__ __align__(16) h16 sA[2 * 64 * 32];    // two k-half slabs
    __shared__ __align__(16) h16 sB[2 * 128 * 32];
    const int tid  = threadIdx.x;
    const int lane = tid & 63;
    const int bswz = blockIdx.x;
    const int slot = bswz & 7;
    const int gg   = bswz >> 3;
    const int mBase = ((gg / NT) * 8 + slot) * 64;
    const int nBase = (gg % NT) * 128;
    const int w  = tid >> 6;
    const int wm = (w >> 1) * 32;      // wave row base (0 or 32)
    const int wn = (w & 1) * 64;       // wave col base (0 or 64)
    const f32x4 zero = {0.f, 0.f, 0.f, 0.f};
    f32x4 acc[2][4];
    #pragma unroll
    for (int i = 0; i < 2; ++i) {
        #pragma unroll
        for (int j = 0; j < 4; ++j) acc[i][j] = zero;
    }

    const int ldR = tid >> 2;          // 0..63
    const int ldC = (tid & 3) * 8;     // k element offset within a 32-slab
    const int lm = lane & 15, lk = (lane >> 4) * 8;

    for (int k0 = 0; k0 < Kt; k0 += 64) {
        const h16* Ab; int Ak, As;     // K1 is a multiple of 64 -> no straddle
        if (k0 < K1) { Ab = A1; Ak = k0;      As = K1; }
        else         { Ab = A2; Ak = k0 - K1; As = K2; }
        const h16* arow = Ab + (size_t)(mBase + ldR) * As + Ak + ldC;
        gload16(arow,      &sA[ldR * 32 + ldC]);
        gload16(arow + 32, &sA[2048 + ldR * 32 + ldC]);
        #pragma unroll
        for (int r = 0; r < 2; ++r) {
            const h16* brow = BT + (size_t)(nBase + r * 64 + ldR) * Kt + k0 + ldC;
            gload16(brow,      &sB[(r * 64 + ldR) * 32 + ldC]);
            gload16(brow + 32, &sB[4096 + (r * 64 + ldR) * 32 + ldC]);
        }
        __syncthreads();
        #pragma unroll
        for (int h = 0; h < 2; ++h) {
            h16x8 af[2], bfr[4];
            #pragma unroll
            for (int i = 0; i < 2; ++i)
                af[i] = *(const h16x8*)&sA[h * 2048 + (wm + i * 16 + lm) * 32 + lk];
            #pragma unroll
            for (int j = 0; j < 4; ++j)
                bfr[j] = *(const h16x8*)&sB[h * 4096 + (wn + j * 16 + lm) * 32 + lk];
            #pragma unroll
            for (int i = 0; i < 2; ++i) {
                #pragma unroll
                for (int j = 0; j < 4; ++j)
                    acc[i][j] = __builtin_amdgcn_mfma_f32_16x16x32_f16(af[i], bfr[j], acc[i][j], 0, 0, 0);
            }
        }
        __syncthreads();
    }

    const int lr4 = (lane >> 4) * 4;
    #pragma unroll
    for (int j = 0; j < 4; ++j) {
        const int col = nBase + wn + j * 16 + lm;
        float bv;
        if (BIASMODE == 0) bv = bias1[col];
        else if (BIASMODE == 1) bv = bias1[col] + b2scale * bias2[col];
        else {
            const int seg = col >> 9;
            const float* bp = seg == 0 ? bias1 : (seg == 1 ? bias2 : bias3);
            bv = bp[col & 511];
        }
        #pragma unroll
        for (int i = 0; i < 2; ++i) {
            const int row0 = mBase + wm + i * 16 + lr4;
            #pragma unroll
            for (int r = 0; r < 4; ++r) {
                float v = acc[i][j][r] + bv;
                if (DOELU) v = eluf(v);
                if (BIASMODE == 2) {
                    if (col < 512) {
                        out[(size_t)(row0 + r) * 512 + col] = (h16)v;
                    } else {
                        __hip_fp8_e4m3 f8(v);
                        out2[(size_t)(row0 + r) * 1024 + (col - 512)] = (unsigned char)f8.__x;
                    }
                } else {
                    out[(size_t)(row0 + r) * N + col] = (h16)v;
                }
            }
        }
    }
}

// ---- layernorm (one wave per 512-row), optional ELU, optional fp32 out ----
template<bool DOELU, bool OUTF32>
__global__ __launch_bounds__(256)
void k_ln(const h16* __restrict__ X, const float* __restrict__ g, const float* __restrict__ b,
          h16* __restrict__ outH, float* __restrict__ outF)
{
    const int row  = blockIdx.x * 4 + (threadIdx.x >> 6);
    const int lane = threadIdx.x & 63;
    const h16x8 xv = *(const h16x8*)(X + (size_t)row * 512 + lane * 8);
    float v[8], s = 0.f, ss = 0.f;
    #pragma unroll
    for (int k = 0; k < 8; ++k) { v[k] = (float)xv[k]; s += v[k]; ss += v[k] * v[k]; }
    #pragma unroll
    for (int m = 1; m < 64; m <<= 1) { s += __shfl_xor(s, m, 64); ss += __shfl_xor(ss, m, 64); }
    const float mean = s * (1.f / 512.f);
    const float var  = ss * (1.f / 512.f) - mean * mean;
    const float rstd = rsqrtf(var + 1e-5f);
    #pragma unroll
    for (int k = 0; k < 8; ++k) {
        const int c = lane * 8 + k;
        float y = (v[k] - mean) * rstd * g[c] + b[c];
        if (DOELU) y = eluf(y);
        if (OUTF32) outF[(size_t)row * 512 + c] = y;
        else        outH[(size_t)row * 512 + c] = (h16)y;
    }
}

// ---- neighbor multi-head attention: ONE WAVE PER NODE, fp8 KV, async LDS gather ----
// fp8 decode via v_cvt_pk_f32_fp8 (4 insts / 8 elems) to cut VALU pressure.
__global__ __launch_bounds__(64)
void k_attn(const h16* __restrict__ Q, const unsigned char* __restrict__ KV,
            const int* __restrict__ nbr, h16* __restrict__ outA)
{
    __shared__ __align__(16) unsigned char sKV[16 * 1024];
    const int n = blockIdx.x;
    const int lane = threadIdx.x;

    #pragma unroll
    for (int j = 0; j < 16; ++j) {
        const int idx = nbr[n * 16 + j];              // wave-uniform -> s_load
        gload16(KV + (size_t)idx * 1024 + lane * 16, &sKV[j * 1024 + lane * 16]);
    }
    const h16x8 qv = *(const h16x8*)&Q[(size_t)n * 512 + lane * 8];

    asm volatile("s_waitcnt vmcnt(0)" ::: "memory");

    float qf[8];
    #pragma unroll
    for (int e = 0; e < 8; ++e) qf[e] = (float)qv[e];

    float s[16];
    #pragma unroll
    for (int j = 0; j < 16; ++j) {
        const uint2 U = *(const uint2*)&sKV[j * 1024 + lane * 8];
        const f32x2 k0 = __builtin_amdgcn_cvt_pk_f32_fp8(U.x, false);
        const f32x2 k1 = __builtin_amdgcn_cvt_pk_f32_fp8(U.x, true);
        const f32x2 k2 = __builtin_amdgcn_cvt_pk_f32_fp8(U.y, false);
        const f32x2 k3 = __builtin_amdgcn_cvt_pk_f32_fp8(U.y, true);
        s[j] = qf[0] * k0.x + qf[1] * k0.y + qf[2] * k1.x + qf[3] * k1.y
             + qf[4] * k2.x + qf[5] * k2.y + qf[6] * k3.x + qf[7] * k3.y;
    }
    #pragma unroll
    for (int m = 1; m < 8; m <<= 1) {
        #pragma unroll
        for (int j = 0; j < 16; ++j) s[j] += __shfl_xor(s[j], m, 64);
    }
    float mx = -1e30f;
    #pragma unroll
    for (int j = 0; j < 16; ++j) { s[j] *= 0.125f; mx = fmaxf(mx, s[j]); }
    float sum = 0.f;
    #pragma unroll
    for (int j = 0; j < 16; ++j) { s[j] = __expf(s[j] - mx); sum += s[j]; }
    const float rinv = 1.f / sum;

    float acc[8];
    #pragma unroll
    for (int e = 0; e < 8; ++e) acc[e] = 0.f;
    #pragma unroll
    for (int j = 0; j < 16; ++j) {
        const float w = s[j] * rinv;
        const uint2 U = *(const uint2*)&sKV[j * 1024 + 512 + lane * 8];
        const f32x2 v0 = __builtin_amdgcn_cvt_pk_f32_fp8(U.x, false);
        const f32x2 v1 = __builtin_amdgcn_cvt_pk_f32_fp8(U.x, true);
        const f32x2 v2 = __builtin_amdgcn_cvt_pk_f32_fp8(U.y, false);
        const f32x2 v3 = __builtin_amdgcn_cvt_pk_f32_fp8(U.y, true);
        acc[0] += w * v0.x; acc[1] += w * v0.y; acc[2] += w * v1.x; acc[3] += w * v1.y;
        acc[4] += w * v2.x; acc[5] += w * v2.y; acc[6] += w * v3.x; acc[7] += w * v3.y;
    }
    h16x8 o;
    #pragma unroll
    for (int e = 0; e < 8; ++e) o[e] = (h16)acc[e];
    *(h16x8*)&outA[(size_t)n * 512 + lane * 8] = o;
}

extern "C" void kernel_launch(void* const* d_in, const int* in_sizes, int n_in,
                              void* d_out, int out_size, void* d_ws, size_t ws_size,
                              hipStream_t stream)
{
    const float* data = (const float*)d_in[0];
    const int*   nbr  = (const int*)d_in[1];
    const float* w0   = (const float*)d_in[2];
    const float* b0   = (const float*)d_in[3];
    const float* w1   = (const float*)d_in[4];
    const float* b1   = (const float*)d_in[5];
    const float* w2   = (const float*)d_in[6];
    const float* b2   = (const float*)d_in[7];
    const float* pdw  = (const float*)d_in[8];
    const float* pdb  = (const float*)d_in[9];
    const float* piw  = (const float*)d_in[10];
    const float* pib  = (const float*)d_in[11];
    const float* qw   = (const float*)d_in[12];
    const float* qb   = (const float*)d_in[13];
    const float* kw   = (const float*)d_in[14];
    const float* kb   = (const float*)d_in[15];
    const float* vw   = (const float*)d_in[16];
    const float* vb   = (const float*)d_in[17];
    const float* ow   = (const float*)d_in[18];
    const float* ob   = (const float*)d_in[19];
    const float* ln1g = (const float*)d_in[20];
    const float* ln1b = (const float*)d_in[21];
    const float* ln2g = (const float*)d_in[22];
    const float* ln2b = (const float*)d_in[23];
    h16*   ws  = (h16*)d_ws;
    float* out = (float*)d_out;
    h16*   qbuf = (h16*)d_out;                          // Q parks in d_out until attn
    unsigned char* kv8 = (unsigned char*)(ws + OFF_X1); // fp8 K|V (X1 dead by then)

    k_cvt_data<<<4096, 256, 0, stream>>>(data, ws + OFF_DATA);
    k_prep_w<<<1920, dim3(32, 8), 0, stream>>>(w0, w1, w2, pdw, qw, kw, vw, ow, piw, ws);

    // X1 = elu(data @ W0 + b0)
    k_gemm<0, true , 4><<<1024, 256, 0, stream>>>(ws + OFF_DATA, nullptr, 256, 0, ws + OFF_W0T,
                                             b0, nullptr, nullptr, 0.f,
                                             ws + OFF_X1, nullptr, 512);
    // X2 = elu(X1 @ W1 + b1)
    k_gemm<0, true , 4><<<1024, 256, 0, stream>>>(ws + OFF_X1, nullptr, 512, 0, ws + OFF_W1T,
                                             b1, nullptr, nullptr, 0.f,
                                             ws + OFF_X2, nullptr, 512);
    // P = X2 @ W2 + 2*(data @ pd_w) + (b2 + 2*pd_b)
    k_gemm<1, false, 4><<<1024, 256, 0, stream>>>(ws + OFF_X2, ws + OFF_DATA, 512, 256, ws + OFF_W2PD,
                                             b2, pdb, nullptr, 2.f,
                                             ws + OFF_P, nullptr, 512);
    // LOCAL = elu(LN(P))  (in-place)
    k_ln<true, false><<<4096, 256, 0, stream>>>(ws + OFF_P, ln1g, ln1b, ws + OFF_P, nullptr);
    // Q(d_out, f16) | KV8(fp8) = LOCAL @ [q|k|v] + bias
    k_gemm<2, false, 12><<<3072, 256, 0, stream>>>(ws + OFF_P, nullptr, 512, 0, ws + OFF_QKVT,
                                             qb, kb, vb, 0.f,
                                             qbuf, kv8, 1536);
    // ATTN (-> P region, LOCAL dead)
    k_attn<<<16384, 64, 0, stream>>>(qbuf, kv8, nbr, ws + OFF_P);
    // PRE2 = ATTN @ o_w + data @ pi_w + (o_b + pi_b)   (-> X1 region, kv8 dead)
    k_gemm<1, false, 4><<<1024, 256, 0, stream>>>(ws + OFF_P, ws + OFF_DATA, 512, 256, ws + OFF_OPIT,
                                             ob, pib, nullptr, 1.f,
                                             ws + OFF_X1, nullptr, 512);
    // out = LN(PRE2)  fp32
    k_ln<false, true><<<4096, 256, 0, stream>>>(ws + OFF_X1, ln2g, ln2b, nullptr, out);
}